// Round 2
// baseline (1230.581 us; speedup 1.0000x reference)
//
#include <hip/hip_runtime.h>
#include <hip/hip_bf16.h>

#define BB 4
#define TT 1024
#define SS 1024
#define EE 768
#define HH 12
#define DD 64
#define BH (BB*HH)          // 48
#define QSCALE 0.125f       // D^-0.5

// ---------------------------------------------------------------------------
// K1/K4: C = (X @ W^T + bias) * scale
// X: [M, 768] row-major; W: [768, 768] row-major (torch Linear weight: [out,in])
// HEAD_LAYOUT=1: out[((b*H+h)*1024 + l)*64 + d]  (m = b*1024+l, n = h*64+d)
// HEAD_LAYOUT=0: out[m*768 + n]
// Tiles: BM=128, BN=64, BK=16; 256 threads; 8x4 micro-tile.
// ---------------------------------------------------------------------------
template<int HEAD_LAYOUT>
__global__ __launch_bounds__(256) void gemm_xwt(
    const float* __restrict__ X, const float* __restrict__ W,
    const float* __restrict__ bias, float* __restrict__ out, float scale)
{
    __shared__ float4 As4[128][5];   // [m][k4], pad 4->5 f4
    __shared__ float4 Bs4[64][5];
    const int bm = blockIdx.x * 128;
    const int bn = blockIdx.y * 64;
    const int tid = threadIdx.x;
    const int tx = tid & 15;         // n = bn + tx + 16j, j<4
    const int ty = tid >> 4;         // m = bm + ty + 16i, i<8

    float acc[8][4];
    #pragma unroll
    for (int i = 0; i < 8; ++i)
        #pragma unroll
        for (int j = 0; j < 4; ++j) acc[i][j] = 0.f;

    for (int k0 = 0; k0 < 768; k0 += 16) {
        {   // A tile: 128 rows x 4 f4 = 512 f4 -> 2 per thread
            int f = tid, r = f >> 2, c4 = f & 3;
            As4[r][c4] = *(const float4*)&X[(size_t)(bm + r) * 768 + k0 + c4 * 4];
            f = tid + 256; r = f >> 2; c4 = f & 3;
            As4[r][c4] = *(const float4*)&X[(size_t)(bm + r) * 768 + k0 + c4 * 4];
            // B tile: 64 rows x 4 f4 = 256 f4 -> 1 per thread
            r = tid >> 2; c4 = tid & 3;
            Bs4[r][c4] = *(const float4*)&W[(size_t)(bn + r) * 768 + k0 + c4 * 4];
        }
        __syncthreads();
        #pragma unroll
        for (int k4 = 0; k4 < 4; ++k4) {
            float4 a4[8], b4[4];
            #pragma unroll
            for (int i = 0; i < 8; ++i) a4[i] = As4[ty + 16 * i][k4];
            #pragma unroll
            for (int j = 0; j < 4; ++j) b4[j] = Bs4[tx + 16 * j][k4];
            #pragma unroll
            for (int i = 0; i < 8; ++i)
                #pragma unroll
                for (int j = 0; j < 4; ++j)
                    acc[i][j] += a4[i].x * b4[j].x + a4[i].y * b4[j].y
                               + a4[i].z * b4[j].z + a4[i].w * b4[j].w;
        }
        __syncthreads();
    }
    #pragma unroll
    for (int i = 0; i < 8; ++i) {
        const int gm = bm + ty + 16 * i;
        #pragma unroll
        for (int j = 0; j < 4; ++j) {
            const int gn = bn + tx + 16 * j;
            const float val = (acc[i][j] + bias[gn]) * scale;
            if (HEAD_LAYOUT) {
                const int b = gm >> 10, l = gm & 1023;
                const int h = gn >> 6,  d = gn & 63;
                out[(size_t)((b * HH + h) * 1024 + l) * 64 + d] = val;
            } else {
                out[(size_t)gm * 768 + gn] = val;
            }
        }
    }
}

// ---------------------------------------------------------------------------
// K2: biasbuf[bh][t][s] = q[bh][t][:] . pos[t][s][:]
// block = (t, s-chunk of 128), 192 threads; pos is read exactly ONCE total.
// Amortizes each pos element across all 48 bh via LDS.
// ---------------------------------------------------------------------------
__global__ __launch_bounds__(192) void bias_fill(
    const float* __restrict__ q, const float* __restrict__ pos,
    float* __restrict__ biasbuf)
{
    const int t  = blockIdx.x;
    const int sc = blockIdx.y;             // s0 = sc*128
    __shared__ float Qs[64][49];           // [d][bh]
    __shared__ float Ps[64][129];          // [d][s_local]
    const int tid = threadIdx.x;

    for (int f = tid; f < 768; f += 192) { // 48 bh x 16 f4 along d
        const int bh = f >> 4, d4 = (f & 15) * 4;
        const float4 w = *(const float4*)&q[(size_t)(bh * 1024 + t) * 64 + d4];
        Qs[d4 + 0][bh] = w.x; Qs[d4 + 1][bh] = w.y;
        Qs[d4 + 2][bh] = w.z; Qs[d4 + 3][bh] = w.w;
    }
    for (int f = tid; f < 2048; f += 192) { // 128 s x 16 f4 along d
        const int sl = f >> 4, d4 = (f & 15) * 4;
        const float4 w = *(const float4*)&pos[((size_t)t * 1024 + sc * 128 + sl) * 64 + d4];
        Ps[d4 + 0][sl] = w.x; Ps[d4 + 1][sl] = w.y;
        Ps[d4 + 2][sl] = w.z; Ps[d4 + 3][sl] = w.w;
    }
    __syncthreads();

    const int sg = tid & 31;   // s = sg + 32u, u<4
    const int g  = tid >> 5;   // bh = g*8 + i, i<8
    float acc[8][4];
    #pragma unroll
    for (int i = 0; i < 8; ++i)
        #pragma unroll
        for (int u = 0; u < 4; ++u) acc[i][u] = 0.f;

    #pragma unroll 4
    for (int d = 0; d < 64; ++d) {
        float p[4], qv[8];
        #pragma unroll
        for (int u = 0; u < 4; ++u) p[u] = Ps[d][sg + 32 * u];
        #pragma unroll
        for (int i = 0; i < 8; ++i) qv[i] = Qs[d][g * 8 + i];
        #pragma unroll
        for (int i = 0; i < 8; ++i)
            #pragma unroll
            for (int u = 0; u < 4; ++u) acc[i][u] += qv[i] * p[u];
    }
    #pragma unroll
    for (int i = 0; i < 8; ++i) {
        const int bh = g * 8 + i;
        #pragma unroll
        for (int u = 0; u < 4; ++u) {
            const int s = sc * 128 + sg + 32 * u;
            biasbuf[((size_t)bh * 1024 + t) * 1024 + s] = acc[i][u];
        }
    }
}

// ---------------------------------------------------------------------------
// K3: fused flash attention.
// Per block: one bh, one 64-row t-tile. Loop s-tiles of 64:
//   S = Q K^T + bias (bias read from biasbuf, written by K2)
//   online softmax (running m,l per row), O += P V.
// Output written as [B, T, E] for the final projection.
// LDS: Q 17.4K + K/P union 17.4K + V^T 17.4K = 52.2K -> 3 blocks/CU.
// ---------------------------------------------------------------------------
__global__ __launch_bounds__(256) void flash_attn(
    const float* __restrict__ q, const float* __restrict__ k,
    const float* __restrict__ v, const float* __restrict__ biasbuf,
    float* __restrict__ attn)
{
    const int mt = blockIdx.x;        // t-tile
    const int bh = blockIdx.y;
    const int b = bh / HH, h = bh % HH;
    const int tid = threadIdx.x;
    const int tx = tid & 15;          // d / s column group
    const int ty = tid >> 4;          // row group

    __shared__ float4 Qs4[64][17];    // Q[t][d] as f4
    __shared__ float4 KP4[64][17];    // K tile, then reused for P (stride 68 floats)
    __shared__ float  Vt[64][68];     // V^T: [d][s]

    // stage Q tile once
    for (int f = tid; f < 1024; f += 256) {
        const int r = f >> 4, c4 = f & 15;
        Qs4[r][c4] = *(const float4*)&q[((size_t)bh * 1024 + mt * 64 + r) * 64 + c4 * 4];
    }

    float o[4][4];
    float mrow[4], lrow[4];
    #pragma unroll
    for (int i = 0; i < 4; ++i) {
        mrow[i] = -1e30f; lrow[i] = 0.f;
        #pragma unroll
        for (int j = 0; j < 4; ++j) o[i][j] = 0.f;
    }

    for (int s0 = 0; s0 < 1024; s0 += 64) {
        // issue bias loads early (independent of LDS)
        float bias_r[4][4];
        #pragma unroll
        for (int i = 0; i < 4; ++i) {
            const size_t row = ((size_t)bh * 1024 + mt * 64 + ty + 16 * i) * 1024;
            #pragma unroll
            for (int j = 0; j < 4; ++j)
                bias_r[i][j] = biasbuf[row + s0 + tx + 16 * j];
        }

        __syncthreads();   // prev iter's P/V reads done (and Q stage on iter 0)
        // stage K tile (row-major f4) and V tile transposed [d][s]
        for (int f = tid; f < 1024; f += 256) {
            const int r = f >> 4, c4 = f & 15;
            KP4[r][c4] = *(const float4*)&k[((size_t)bh * 1024 + s0 + r) * 64 + c4 * 4];
        }
        for (int f = tid; f < 1024; f += 256) {
            const int r = f & 63, c4 = f >> 6;  // r = s_local, c4 = d4
            const float4 w = *(const float4*)&v[((size_t)bh * 1024 + s0 + r) * 64 + c4 * 4];
            Vt[c4 * 4 + 0][r] = w.x; Vt[c4 * 4 + 1][r] = w.y;
            Vt[c4 * 4 + 2][r] = w.z; Vt[c4 * 4 + 3][r] = w.w;
        }
        __syncthreads();

        // S = Q K^T + bias
        float accs[4][4];
        #pragma unroll
        for (int i = 0; i < 4; ++i)
            #pragma unroll
            for (int j = 0; j < 4; ++j) accs[i][j] = bias_r[i][j];
        #pragma unroll
        for (int k4 = 0; k4 < 16; ++k4) {
            float4 a4[4], b4[4];
            #pragma unroll
            for (int i = 0; i < 4; ++i) a4[i] = Qs4[ty + 16 * i][k4];
            #pragma unroll
            for (int j = 0; j < 4; ++j) b4[j] = KP4[tx + 16 * j][k4];
            #pragma unroll
            for (int i = 0; i < 4; ++i)
                #pragma unroll
                for (int j = 0; j < 4; ++j)
                    accs[i][j] += a4[i].x * b4[j].x + a4[i].y * b4[j].y
                                + a4[i].z * b4[j].z + a4[i].w * b4[j].w;
        }

        // online softmax update (rows r = ty + 16i, owned by 16 lanes tx)
        float p[4][4];
        #pragma unroll
        for (int i = 0; i < 4; ++i) {
            float tmax = fmaxf(fmaxf(accs[i][0], accs[i][1]),
                               fmaxf(accs[i][2], accs[i][3]));
            #pragma unroll
            for (int off = 8; off > 0; off >>= 1)
                tmax = fmaxf(tmax, __shfl_xor(tmax, off, 16));
            const float newm = fmaxf(mrow[i], tmax);
            const float scale = __expf(mrow[i] - newm);
            float psum = 0.f;
            #pragma unroll
            for (int j = 0; j < 4; ++j) {
                p[i][j] = __expf(accs[i][j] - newm);
                psum += p[i][j];
            }
            #pragma unroll
            for (int off = 8; off > 0; off >>= 1)
                psum += __shfl_xor(psum, off, 16);
            lrow[i] = lrow[i] * scale + psum;
            mrow[i] = newm;
            #pragma unroll
            for (int j = 0; j < 4; ++j) o[i][j] *= scale;
        }

        __syncthreads();   // all K reads done; safe to overwrite with P
        {   // write P into KP4 region: Pf[t * 68 + s]
            float* Pf = (float*)KP4;
            #pragma unroll
            for (int i = 0; i < 4; ++i)
                #pragma unroll
                for (int j = 0; j < 4; ++j)
                    Pf[(ty + 16 * i) * 68 + tx + 16 * j] = p[i][j];
        }
        __syncthreads();   // P visible

        // O += P V  (K dim = 64 s-values)
        {
            const float* Pf = (const float*)KP4;
            #pragma unroll 4
            for (int sk4 = 0; sk4 < 16; ++sk4) {
                float4 p4[4], v4[4];
                #pragma unroll
                for (int i = 0; i < 4; ++i)
                    p4[i] = *(const float4*)&Pf[(ty + 16 * i) * 68 + sk4 * 4];
                #pragma unroll
                for (int j = 0; j < 4; ++j)
                    v4[j] = *(const float4*)&Vt[tx + 16 * j][sk4 * 4];
                #pragma unroll
                for (int i = 0; i < 4; ++i)
                    #pragma unroll
                    for (int j = 0; j < 4; ++j)
                        o[i][j] += p4[i].x * v4[j].x + p4[i].y * v4[j].y
                                 + p4[i].z * v4[j].z + p4[i].w * v4[j].w;
            }
        }
    }

    // epilogue: normalize and write [B,T,E]
    #pragma unroll
    for (int i = 0; i < 4; ++i) {
        const int t = mt * 64 + ty + 16 * i;
        const float inv = 1.0f / lrow[i];
        #pragma unroll
        for (int j = 0; j < 4; ++j) {
            const int d = tx + 16 * j;
            attn[((size_t)b * 1024 + t) * 768 + h * 64 + d] = o[i][j] * inv;
        }
    }
}

// ---------------------------------------------------------------------------
extern "C" void kernel_launch(void* const* d_in, const int* in_sizes, int n_in,
                              void* d_out, int out_size, void* d_ws, size_t ws_size,
                              hipStream_t stream)
{
    const float* hidden = (const float*)d_in[0];
    const float* kv     = (const float*)d_in[1];
    const float* pos    = (const float*)d_in[2];
    const float* Wq = (const float*)d_in[3];  const float* bq = (const float*)d_in[4];
    const float* Wk = (const float*)d_in[5];  const float* bk = (const float*)d_in[6];
    const float* Wv = (const float*)d_in[7];  const float* bv = (const float*)d_in[8];
    const float* Wo = (const float*)d_in[9];  const float* bo = (const float*)d_in[10];
    float* out = (float*)d_out;

    // workspace (floats): q,k,v: 48*1024*64 each; attn: 4*1024*768; bias: 48*1024*1024
    float* q       = (float*)d_ws;
    float* kbuf    = q     + (size_t)BH * 1024 * 64;
    float* vbuf    = kbuf  + (size_t)BH * 1024 * 64;
    float* attn    = vbuf  + (size_t)BH * 1024 * 64;
    float* biasbuf = attn  + (size_t)BB * 1024 * EE;   // total ~252 MB

    const dim3 gproj(32, 12), blk(256);
    gemm_xwt<1><<<gproj, blk, 0, stream>>>(hidden, Wq, bq, q,    QSCALE);
    gemm_xwt<1><<<gproj, blk, 0, stream>>>(kv,     Wk, bk, kbuf, 1.0f);
    gemm_xwt<1><<<gproj, blk, 0, stream>>>(kv,     Wv, bv, vbuf, 1.0f);

    bias_fill <<<dim3(1024, 8), 192, 0, stream>>>(q, pos, biasbuf);
    flash_attn<<<dim3(16, 48),  256, 0, stream>>>(q, kbuf, vbuf, biasbuf, attn);

    gemm_xwt<0><<<gproj, blk, 0, stream>>>(attn, Wo, bo, out, 1.0f);
}

// Round 3
// 912.749 us; speedup vs baseline: 1.3482x; 1.3482x over previous
//
#include <hip/hip_runtime.h>
#include <hip/hip_bf16.h>

#define BB 4
#define TT 1024
#define SS 1024
#define EE 768
#define HH 12
#define DD 64
#define BH (BB*HH)          // 48
#define QSCALE 0.125f       // D^-0.5

typedef __attribute__((ext_vector_type(8))) short bf16x8;
typedef __attribute__((ext_vector_type(4))) float f32x4;

// ---- fp32 -> bf16 split helpers (RNE) --------------------------------------
__device__ __forceinline__ unsigned short bf16_rne(float x) {
    unsigned u = __builtin_bit_cast(unsigned, x);
    u += 0x7FFFu + ((u >> 16) & 1u);
    return (unsigned short)(u >> 16);
}
__device__ __forceinline__ void split_bf16(float x, unsigned short& h, unsigned short& l) {
    unsigned u = __builtin_bit_cast(unsigned, x);
    unsigned r = u + 0x7FFFu + ((u >> 16) & 1u);
    h = (unsigned short)(r >> 16);
    const float fh = __builtin_bit_cast(float, r & 0xFFFF0000u);
    l = bf16_rne(x - fh);
}

// ---------------------------------------------------------------------------
// C = (X @ W^T + bias) * scale via split-bf16 MFMA (3 mfma per product term):
//   X = Xh + Xl, W = Wh + Wl;  D += Xh*Wh + Xh*Wl + Xl*Wh   (fp32 accum)
// X: [M,768] rm; W: [N,768] rm (torch Linear weight). Both operands are
// [row][k] -> identical frag load scheme (intra-lane k permutation cancels).
// BM=128, BN=64, BK=32; 256 thr (4 waves, each a 64x32 out tile).
// HEAD_LAYOUT=1: out[((b*H+h)*1024+l)*64+d]; else out[m*768+n].
// ---------------------------------------------------------------------------
template<int HEAD_LAYOUT>
__global__ __launch_bounds__(256) void gemm_xwt_mfma(
    const float* __restrict__ X, const float* __restrict__ W,
    const float* __restrict__ bias, float* __restrict__ out, float scale)
{
    // row stride 40 shorts = 80B: bank stride 20 -> <=2-way conflicts on b128
    __shared__ __align__(16) unsigned short Ah[128][40], Al[128][40];
    __shared__ __align__(16) unsigned short Bh[64][40],  Bl[64][40];

    const int bm = blockIdx.x * 128, bn = blockIdx.y * 64;
    const int tid  = threadIdx.x;
    const int wave = tid >> 6, lane = tid & 63;
    const int wr = (wave >> 1) * 64;   // wave row offset in block tile
    const int wc = (wave & 1) * 32;    // wave col offset
    const int lr = lane & 15;          // frag row (A) / col (B)
    const int lg = lane >> 4;          // k-group (8 elems each)

    f32x4 acc[4][2];
    #pragma unroll
    for (int mi = 0; mi < 4; ++mi)
        #pragma unroll
        for (int nj = 0; nj < 2; ++nj) acc[mi][nj] = (f32x4){0.f, 0.f, 0.f, 0.f};

    for (int k0 = 0; k0 < 768; k0 += 32) {
        // stage A tile: 128 rows x 8 f4 = 1024 f4 -> 4 per thread
        #pragma unroll
        for (int i = 0; i < 4; ++i) {
            const int f = i * 256 + tid, r = f >> 3, c = (f & 7) * 4;
            const float4 v = *(const float4*)&X[(size_t)(bm + r) * 768 + k0 + c];
            unsigned short h0,h1,h2,h3,l0,l1,l2,l3;
            split_bf16(v.x, h0, l0); split_bf16(v.y, h1, l1);
            split_bf16(v.z, h2, l2); split_bf16(v.w, h3, l3);
            *(ushort4*)&Ah[r][c] = make_ushort4(h0, h1, h2, h3);
            *(ushort4*)&Al[r][c] = make_ushort4(l0, l1, l2, l3);
        }
        // stage B tile: 64 rows x 8 f4 = 512 f4 -> 2 per thread
        #pragma unroll
        for (int i = 0; i < 2; ++i) {
            const int f = i * 256 + tid, r = f >> 3, c = (f & 7) * 4;
            const float4 v = *(const float4*)&W[(size_t)(bn + r) * 768 + k0 + c];
            unsigned short h0,h1,h2,h3,l0,l1,l2,l3;
            split_bf16(v.x, h0, l0); split_bf16(v.y, h1, l1);
            split_bf16(v.z, h2, l2); split_bf16(v.w, h3, l3);
            *(ushort4*)&Bh[r][c] = make_ushort4(h0, h1, h2, h3);
            *(ushort4*)&Bl[r][c] = make_ushort4(l0, l1, l2, l3);
        }
        __syncthreads();

        bf16x8 ah[4], al[4], bh[2], bl[2];
        #pragma unroll
        for (int mi = 0; mi < 4; ++mi) {
            ah[mi] = *(const bf16x8*)&Ah[wr + mi * 16 + lr][lg * 8];
            al[mi] = *(const bf16x8*)&Al[wr + mi * 16 + lr][lg * 8];
        }
        #pragma unroll
        for (int nj = 0; nj < 2; ++nj) {
            bh[nj] = *(const bf16x8*)&Bh[wc + nj * 16 + lr][lg * 8];
            bl[nj] = *(const bf16x8*)&Bl[wc + nj * 16 + lr][lg * 8];
        }
        #pragma unroll
        for (int mi = 0; mi < 4; ++mi)
            #pragma unroll
            for (int nj = 0; nj < 2; ++nj) {
                acc[mi][nj] = __builtin_amdgcn_mfma_f32_16x16x32_bf16(ah[mi], bl[nj], acc[mi][nj], 0, 0, 0);
                acc[mi][nj] = __builtin_amdgcn_mfma_f32_16x16x32_bf16(al[mi], bh[nj], acc[mi][nj], 0, 0, 0);
                acc[mi][nj] = __builtin_amdgcn_mfma_f32_16x16x32_bf16(ah[mi], bh[nj], acc[mi][nj], 0, 0, 0);
            }
        __syncthreads();
    }

    // epilogue: D[row=(lane>>4)*4+r][col=lane&15] (m89-verified mapping)
    #pragma unroll
    for (int mi = 0; mi < 4; ++mi) {
        #pragma unroll
        for (int nj = 0; nj < 2; ++nj) {
            const int gn = bn + wc + nj * 16 + lr;
            #pragma unroll
            for (int r = 0; r < 4; ++r) {
                const int gm = bm + wr + mi * 16 + lg * 4 + r;
                const float val = (acc[mi][nj][r] + bias[gn]) * scale;
                if (HEAD_LAYOUT) {
                    const int b = gm >> 10, l = gm & 1023;
                    const int h = gn >> 6,  d = gn & 63;
                    out[(size_t)((b * HH + h) * 1024 + l) * 64 + d] = val;
                } else {
                    out[(size_t)gm * 768 + gn] = val;
                }
            }
        }
    }
}

// ---------------------------------------------------------------------------
// K2: biasbuf[bh][t][s] = q[bh][t][:] . pos[t][s][:]   (pos read exactly once)
// ---------------------------------------------------------------------------
__global__ __launch_bounds__(192) void bias_fill(
    const float* __restrict__ q, const float* __restrict__ pos,
    float* __restrict__ biasbuf)
{
    const int t  = blockIdx.x;
    const int sc = blockIdx.y;
    __shared__ float Qs[64][49];
    __shared__ float Ps[64][129];
    const int tid = threadIdx.x;

    for (int f = tid; f < 768; f += 192) {
        const int bh = f >> 4, d4 = (f & 15) * 4;
        const float4 w = *(const float4*)&q[(size_t)(bh * 1024 + t) * 64 + d4];
        Qs[d4 + 0][bh] = w.x; Qs[d4 + 1][bh] = w.y;
        Qs[d4 + 2][bh] = w.z; Qs[d4 + 3][bh] = w.w;
    }
    for (int f = tid; f < 2048; f += 192) {
        const int sl = f >> 4, d4 = (f & 15) * 4;
        const float4 w = *(const float4*)&pos[((size_t)t * 1024 + sc * 128 + sl) * 64 + d4];
        Ps[d4 + 0][sl] = w.x; Ps[d4 + 1][sl] = w.y;
        Ps[d4 + 2][sl] = w.z; Ps[d4 + 3][sl] = w.w;
    }
    __syncthreads();

    const int sg = tid & 31;
    const int g  = tid >> 5;
    float acc[8][4];
    #pragma unroll
    for (int i = 0; i < 8; ++i)
        #pragma unroll
        for (int u = 0; u < 4; ++u) acc[i][u] = 0.f;

    #pragma unroll 4
    for (int d = 0; d < 64; ++d) {
        float p[4], qv[8];
        #pragma unroll
        for (int u = 0; u < 4; ++u) p[u] = Ps[d][sg + 32 * u];
        #pragma unroll
        for (int i = 0; i < 8; ++i) qv[i] = Qs[d][g * 8 + i];
        #pragma unroll
        for (int i = 0; i < 8; ++i)
            #pragma unroll
            for (int u = 0; u < 4; ++u) acc[i][u] += qv[i] * p[u];
    }
    #pragma unroll
    for (int i = 0; i < 8; ++i) {
        const int bh = g * 8 + i;
        #pragma unroll
        for (int u = 0; u < 4; ++u) {
            const int s = sc * 128 + sg + 32 * u;
            biasbuf[((size_t)bh * 1024 + t) * 1024 + s] = acc[i][u];
        }
    }
}

// ---------------------------------------------------------------------------
// K3: fused flash attention (fp32, unchanged from passing version).
// ---------------------------------------------------------------------------
__global__ __launch_bounds__(256) void flash_attn(
    const float* __restrict__ q, const float* __restrict__ k,
    const float* __restrict__ v, const float* __restrict__ biasbuf,
    float* __restrict__ attn)
{
    const int mt = blockIdx.x;
    const int bh = blockIdx.y;
    const int b = bh / HH, h = bh % HH;
    const int tid = threadIdx.x;
    const int tx = tid & 15;
    const int ty = tid >> 4;

    __shared__ float4 Qs4[64][17];
    __shared__ float4 KP4[64][17];
    __shared__ float  Vt[64][68];

    for (int f = tid; f < 1024; f += 256) {
        const int r = f >> 4, c4 = f & 15;
        Qs4[r][c4] = *(const float4*)&q[((size_t)bh * 1024 + mt * 64 + r) * 64 + c4 * 4];
    }

    float o[4][4];
    float mrow[4], lrow[4];
    #pragma unroll
    for (int i = 0; i < 4; ++i) {
        mrow[i] = -1e30f; lrow[i] = 0.f;
        #pragma unroll
        for (int j = 0; j < 4; ++j) o[i][j] = 0.f;
    }

    for (int s0 = 0; s0 < 1024; s0 += 64) {
        float bias_r[4][4];
        #pragma unroll
        for (int i = 0; i < 4; ++i) {
            const size_t row = ((size_t)bh * 1024 + mt * 64 + ty + 16 * i) * 1024;
            #pragma unroll
            for (int j = 0; j < 4; ++j)
                bias_r[i][j] = biasbuf[row + s0 + tx + 16 * j];
        }

        __syncthreads();
        for (int f = tid; f < 1024; f += 256) {
            const int r = f >> 4, c4 = f & 15;
            KP4[r][c4] = *(const float4*)&k[((size_t)bh * 1024 + s0 + r) * 64 + c4 * 4];
        }
        for (int f = tid; f < 1024; f += 256) {
            const int r = f & 63, c4 = f >> 6;
            const float4 w = *(const float4*)&v[((size_t)bh * 1024 + s0 + r) * 64 + c4 * 4];
            Vt[c4 * 4 + 0][r] = w.x; Vt[c4 * 4 + 1][r] = w.y;
            Vt[c4 * 4 + 2][r] = w.z; Vt[c4 * 4 + 3][r] = w.w;
        }
        __syncthreads();

        float accs[4][4];
        #pragma unroll
        for (int i = 0; i < 4; ++i)
            #pragma unroll
            for (int j = 0; j < 4; ++j) accs[i][j] = bias_r[i][j];
        #pragma unroll
        for (int k4 = 0; k4 < 16; ++k4) {
            float4 a4[4], b4[4];
            #pragma unroll
            for (int i = 0; i < 4; ++i) a4[i] = Qs4[ty + 16 * i][k4];
            #pragma unroll
            for (int j = 0; j < 4; ++j) b4[j] = KP4[tx + 16 * j][k4];
            #pragma unroll
            for (int i = 0; i < 4; ++i)
                #pragma unroll
                for (int j = 0; j < 4; ++j)
                    accs[i][j] += a4[i].x * b4[j].x + a4[i].y * b4[j].y
                                + a4[i].z * b4[j].z + a4[i].w * b4[j].w;
        }

        float p[4][4];
        #pragma unroll
        for (int i = 0; i < 4; ++i) {
            float tmax = fmaxf(fmaxf(accs[i][0], accs[i][1]),
                               fmaxf(accs[i][2], accs[i][3]));
            #pragma unroll
            for (int off = 8; off > 0; off >>= 1)
                tmax = fmaxf(tmax, __shfl_xor(tmax, off, 16));
            const float newm = fmaxf(mrow[i], tmax);
            const float scale = __expf(mrow[i] - newm);
            float psum = 0.f;
            #pragma unroll
            for (int j = 0; j < 4; ++j) {
                p[i][j] = __expf(accs[i][j] - newm);
                psum += p[i][j];
            }
            #pragma unroll
            for (int off = 8; off > 0; off >>= 1)
                psum += __shfl_xor(psum, off, 16);
            lrow[i] = lrow[i] * scale + psum;
            mrow[i] = newm;
            #pragma unroll
            for (int j = 0; j < 4; ++j) o[i][j] *= scale;
        }

        __syncthreads();
        {
            float* Pf = (float*)KP4;
            #pragma unroll
            for (int i = 0; i < 4; ++i)
                #pragma unroll
                for (int j = 0; j < 4; ++j)
                    Pf[(ty + 16 * i) * 68 + tx + 16 * j] = p[i][j];
        }
        __syncthreads();

        {
            const float* Pf = (const float*)KP4;
            #pragma unroll 4
            for (int sk4 = 0; sk4 < 16; ++sk4) {
                float4 p4[4], v4[4];
                #pragma unroll
                for (int i = 0; i < 4; ++i)
                    p4[i] = *(const float4*)&Pf[(ty + 16 * i) * 68 + sk4 * 4];
                #pragma unroll
                for (int j = 0; j < 4; ++j)
                    v4[j] = *(const float4*)&Vt[tx + 16 * j][sk4 * 4];
                #pragma unroll
                for (int i = 0; i < 4; ++i)
                    #pragma unroll
                    for (int j = 0; j < 4; ++j)
                        o[i][j] += p4[i].x * v4[j].x + p4[i].y * v4[j].y
                                 + p4[i].z * v4[j].z + p4[i].w * v4[j].w;
            }
        }
    }

    #pragma unroll
    for (int i = 0; i < 4; ++i) {
        const int t = mt * 64 + ty + 16 * i;
        const float inv = 1.0f / lrow[i];
        #pragma unroll
        for (int j = 0; j < 4; ++j) {
            const int d = tx + 16 * j;
            attn[((size_t)b * 1024 + t) * 768 + h * 64 + d] = o[i][j] * inv;
        }
    }
}

// ---------------------------------------------------------------------------
extern "C" void kernel_launch(void* const* d_in, const int* in_sizes, int n_in,
                              void* d_out, int out_size, void* d_ws, size_t ws_size,
                              hipStream_t stream)
{
    const float* hidden = (const float*)d_in[0];
    const float* kv     = (const float*)d_in[1];
    const float* pos    = (const float*)d_in[2];
    const float* Wq = (const float*)d_in[3];  const float* bq = (const float*)d_in[4];
    const float* Wk = (const float*)d_in[5];  const float* bk = (const float*)d_in[6];
    const float* Wv = (const float*)d_in[7];  const float* bv = (const float*)d_in[8];
    const float* Wo = (const float*)d_in[9];  const float* bo = (const float*)d_in[10];
    float* out = (float*)d_out;

    float* q       = (float*)d_ws;
    float* kbuf    = q     + (size_t)BH * 1024 * 64;
    float* vbuf    = kbuf  + (size_t)BH * 1024 * 64;
    float* attn    = vbuf  + (size_t)BH * 1024 * 64;
    float* biasbuf = attn  + (size_t)BB * 1024 * EE;   // total ~252 MB

    const dim3 gproj(32, 12), blk(256);
    gemm_xwt_mfma<1><<<gproj, blk, 0, stream>>>(hidden, Wq, bq, q,    QSCALE);
    gemm_xwt_mfma<1><<<gproj, blk, 0, stream>>>(kv,     Wk, bk, kbuf, 1.0f);
    gemm_xwt_mfma<1><<<gproj, blk, 0, stream>>>(kv,     Wv, bv, vbuf, 1.0f);

    bias_fill <<<dim3(1024, 8), 192, 0, stream>>>(q, pos, biasbuf);
    flash_attn<<<dim3(16, 48),  256, 0, stream>>>(q, kbuf, vbuf, biasbuf, attn);

    gemm_xwt_mfma<0><<<gproj, blk, 0, stream>>>(attn, Wo, bo, out, 1.0f);
}

// Round 9
// 800.659 us; speedup vs baseline: 1.5370x; 1.1400x over previous
//
#include <hip/hip_runtime.h>
#include <hip/hip_bf16.h>

#define BB 4
#define TT 1024
#define SS 1024
#define EE 768
#define HH 12
#define DD 64
#define BH (BB*HH)          // 48
#define QSCALE 0.125f       // D^-0.5

typedef __attribute__((ext_vector_type(8))) short bf16x8;
typedef __attribute__((ext_vector_type(4))) float f32x4;

// ---- fp32 -> bf16 split helpers (RNE) --------------------------------------
__device__ __forceinline__ unsigned short bf16_rne(float x) {
    unsigned u = __builtin_bit_cast(unsigned, x);
    u += 0x7FFFu + ((u >> 16) & 1u);
    return (unsigned short)(u >> 16);
}
__device__ __forceinline__ void split_bf16(float x, unsigned short& h, unsigned short& l) {
    unsigned u = __builtin_bit_cast(unsigned, x);
    unsigned r = u + 0x7FFFu + ((u >> 16) & 1u);
    h = (unsigned short)(r >> 16);
    const float fh = __builtin_bit_cast(float, r & 0xFFFF0000u);
    l = bf16_rne(x - fh);
}

// ---------------------------------------------------------------------------
// C = (X @ W^T + bias) * scale via split-bf16 MFMA (3 mfma per product term).
// BM=128, BN=64, BK=32; 256 thr (4 waves, each a 64x32 out tile).
// ---------------------------------------------------------------------------
template<int HEAD_LAYOUT>
__global__ __launch_bounds__(256) void gemm_xwt_mfma(
    const float* __restrict__ X, const float* __restrict__ W,
    const float* __restrict__ bias, float* __restrict__ out, float scale)
{
    __shared__ __align__(16) unsigned short Ah[128][40], Al[128][40];
    __shared__ __align__(16) unsigned short Bh[64][40],  Bl[64][40];

    const int bm = blockIdx.x * 128, bn = blockIdx.y * 64;
    const int tid  = threadIdx.x;
    const int wave = tid >> 6, lane = tid & 63;
    const int wr = (wave >> 1) * 64;
    const int wc = (wave & 1) * 32;
    const int lr = lane & 15;
    const int lg = lane >> 4;

    f32x4 acc[4][2];
    #pragma unroll
    for (int mi = 0; mi < 4; ++mi)
        #pragma unroll
        for (int nj = 0; nj < 2; ++nj) acc[mi][nj] = (f32x4){0.f, 0.f, 0.f, 0.f};

    for (int k0 = 0; k0 < 768; k0 += 32) {
        #pragma unroll
        for (int i = 0; i < 4; ++i) {
            const int f = i * 256 + tid, r = f >> 3, c = (f & 7) * 4;
            const float4 v = *(const float4*)&X[(size_t)(bm + r) * 768 + k0 + c];
            unsigned short h0,h1,h2,h3,l0,l1,l2,l3;
            split_bf16(v.x, h0, l0); split_bf16(v.y, h1, l1);
            split_bf16(v.z, h2, l2); split_bf16(v.w, h3, l3);
            *(ushort4*)&Ah[r][c] = make_ushort4(h0, h1, h2, h3);
            *(ushort4*)&Al[r][c] = make_ushort4(l0, l1, l2, l3);
        }
        #pragma unroll
        for (int i = 0; i < 2; ++i) {
            const int f = i * 256 + tid, r = f >> 3, c = (f & 7) * 4;
            const float4 v = *(const float4*)&W[(size_t)(bn + r) * 768 + k0 + c];
            unsigned short h0,h1,h2,h3,l0,l1,l2,l3;
            split_bf16(v.x, h0, l0); split_bf16(v.y, h1, l1);
            split_bf16(v.z, h2, l2); split_bf16(v.w, h3, l3);
            *(ushort4*)&Bh[r][c] = make_ushort4(h0, h1, h2, h3);
            *(ushort4*)&Bl[r][c] = make_ushort4(l0, l1, l2, l3);
        }
        __syncthreads();

        bf16x8 ah[4], al[4], bh[2], bl[2];
        #pragma unroll
        for (int mi = 0; mi < 4; ++mi) {
            ah[mi] = *(const bf16x8*)&Ah[wr + mi * 16 + lr][lg * 8];
            al[mi] = *(const bf16x8*)&Al[wr + mi * 16 + lr][lg * 8];
        }
        #pragma unroll
        for (int nj = 0; nj < 2; ++nj) {
            bh[nj] = *(const bf16x8*)&Bh[wc + nj * 16 + lr][lg * 8];
            bl[nj] = *(const bf16x8*)&Bl[wc + nj * 16 + lr][lg * 8];
        }
        #pragma unroll
        for (int mi = 0; mi < 4; ++mi)
            #pragma unroll
            for (int nj = 0; nj < 2; ++nj) {
                acc[mi][nj] = __builtin_amdgcn_mfma_f32_16x16x32_bf16(ah[mi], bl[nj], acc[mi][nj], 0, 0, 0);
                acc[mi][nj] = __builtin_amdgcn_mfma_f32_16x16x32_bf16(al[mi], bh[nj], acc[mi][nj], 0, 0, 0);
                acc[mi][nj] = __builtin_amdgcn_mfma_f32_16x16x32_bf16(ah[mi], bh[nj], acc[mi][nj], 0, 0, 0);
            }
        __syncthreads();
    }

    #pragma unroll
    for (int mi = 0; mi < 4; ++mi) {
        #pragma unroll
        for (int nj = 0; nj < 2; ++nj) {
            const int gn = bn + wc + nj * 16 + lr;
            #pragma unroll
            for (int r = 0; r < 4; ++r) {
                const int gm = bm + wr + mi * 16 + lg * 4 + r;
                const float val = (acc[mi][nj][r] + bias[gn]) * scale;
                if (HEAD_LAYOUT) {
                    const int b = gm >> 10, l = gm & 1023;
                    const int h = gn >> 6,  d = gn & 63;
                    out[(size_t)((b * HH + h) * 1024 + l) * 64 + d] = val;
                } else {
                    out[(size_t)gm * 768 + gn] = val;
                }
            }
        }
    }
}

// ---------------------------------------------------------------------------
// K2: biasbuf[bh][t][s] = q[bh][t][:] . pos[t][s][:]   (pos read exactly once)
// ---------------------------------------------------------------------------
__global__ __launch_bounds__(192) void bias_fill(
    const float* __restrict__ q, const float* __restrict__ pos,
    float* __restrict__ biasbuf)
{
    const int t  = blockIdx.x;
    const int sc = blockIdx.y;
    __shared__ float Qs[64][49];
    __shared__ float Ps[64][129];
    const int tid = threadIdx.x;

    for (int f = tid; f < 768; f += 192) {
        const int bh = f >> 4, d4 = (f & 15) * 4;
        const float4 w = *(const float4*)&q[(size_t)(bh * 1024 + t) * 64 + d4];
        Qs[d4 + 0][bh] = w.x; Qs[d4 + 1][bh] = w.y;
        Qs[d4 + 2][bh] = w.z; Qs[d4 + 3][bh] = w.w;
    }
    for (int f = tid; f < 2048; f += 192) {
        const int sl = f >> 4, d4 = (f & 15) * 4;
        const float4 w = *(const float4*)&pos[((size_t)t * 1024 + sc * 128 + sl) * 64 + d4];
        Ps[d4 + 0][sl] = w.x; Ps[d4 + 1][sl] = w.y;
        Ps[d4 + 2][sl] = w.z; Ps[d4 + 3][sl] = w.w;
    }
    __syncthreads();

    const int sg = tid & 31;
    const int g  = tid >> 5;
    float acc[8][4];
    #pragma unroll
    for (int i = 0; i < 8; ++i)
        #pragma unroll
        for (int u = 0; u < 4; ++u) acc[i][u] = 0.f;

    #pragma unroll 4
    for (int d = 0; d < 64; ++d) {
        float p[4], qv[8];
        #pragma unroll
        for (int u = 0; u < 4; ++u) p[u] = Ps[d][sg + 32 * u];
        #pragma unroll
        for (int i = 0; i < 8; ++i) qv[i] = Qs[d][g * 8 + i];
        #pragma unroll
        for (int i = 0; i < 8; ++i)
            #pragma unroll
            for (int u = 0; u < 4; ++u) acc[i][u] += qv[i] * p[u];
    }
    #pragma unroll
    for (int i = 0; i < 8; ++i) {
        const int bh = g * 8 + i;
        #pragma unroll
        for (int u = 0; u < 4; ++u) {
            const int s = sc * 128 + sg + 32 * u;
            biasbuf[((size_t)bh * 1024 + t) * 1024 + s] = acc[i][u];
        }
    }
}

// ---------------------------------------------------------------------------
// K3: fused flash attention via MFMA.
// Block = (bh, 64-t tile), 4 waves each owning a 16-row strip.
// QK^T: split-bf16 (3 MFMA) with fp32 bias preloaded into the accumulator.
// P, V: plain bf16 (1 MFMA) — linear error path, negligible.
// P roundtrips through wave-private LDS rows (no block barrier needed).
// LDS: Kh/Kl/Vt/P [64][72]u16 + BiasT[64][64]f32 = 53248 B -> 3 blocks/CU.
// ---------------------------------------------------------------------------
__global__ __launch_bounds__(256) void flash_attn_mfma(
    const float* __restrict__ q, const float* __restrict__ k,
    const float* __restrict__ v, const float* __restrict__ biasbuf,
    float* __restrict__ attn)
{
    __shared__ __align__(16) unsigned short Kh[64][72], Kl[64][72];
    __shared__ __align__(16) unsigned short Vt[64][72], Pm[64][72];
    __shared__ __align__(16) float BiasT[64][64];

    const int bid = blockIdx.x;
    const int vid = (bid & 7) * 96 + (bid >> 3);   // bijective XCD chunk swizzle
    const int mt = vid & 15;
    const int bh = vid >> 4;
    const int b = bh / HH, h = bh % HH;
    const int tid = threadIdx.x;
    const int wave = tid >> 6, lane = tid & 63;
    const int lr = lane & 15, lg = lane >> 4;
    const int trow = wave * 16;                    // wave's local t-strip base

    // --- Q fragments in registers (split-bf16), loaded once ---
    bf16x8 qh[2], ql[2];
    {
        const size_t qbase = ((size_t)bh * 1024 + mt * 64 + trow + lr) * 64;
        #pragma unroll
        for (int kst = 0; kst < 2; ++kst) {
            const float4 x0 = *(const float4*)&q[qbase + kst * 32 + lg * 8];
            const float4 x1 = *(const float4*)&q[qbase + kst * 32 + lg * 8 + 4];
            const float xs[8] = {x0.x, x0.y, x0.z, x0.w, x1.x, x1.y, x1.z, x1.w};
            #pragma unroll
            for (int j = 0; j < 8; ++j) {
                unsigned short hh, ll; split_bf16(xs[j], hh, ll);
                qh[kst][j] = (short)hh; ql[kst][j] = (short)ll;
            }
        }
    }

    f32x4 o[4];
    float mrow[4], lrow[4];
    #pragma unroll
    for (int r = 0; r < 4; ++r) { mrow[r] = -1e30f; lrow[r] = 0.f; }
    #pragma unroll
    for (int nj = 0; nj < 4; ++nj) o[nj] = (f32x4){0.f, 0.f, 0.f, 0.f};

    for (int s0 = 0; s0 < 1024; s0 += 64) {
        __syncthreads();   // prev iteration's LDS reads complete
        // --- stage K (split bf16), V^T (bf16), bias tile (f32) ---
        #pragma unroll
        for (int i = 0; i < 4; ++i) {
            const int idx = i * 256 + tid;
            const int row = idx >> 4, c = (idx & 15) * 4;
            const float4 kk = *(const float4*)&k[((size_t)bh * 1024 + s0 + row) * 64 + c];
            unsigned short h0,h1,h2,h3,l0,l1,l2,l3;
            split_bf16(kk.x, h0, l0); split_bf16(kk.y, h1, l1);
            split_bf16(kk.z, h2, l2); split_bf16(kk.w, h3, l3);
            *(ushort4*)&Kh[row][c] = make_ushort4(h0, h1, h2, h3);
            *(ushort4*)&Kl[row][c] = make_ushort4(l0, l1, l2, l3);
            const float4 vv = *(const float4*)&v[((size_t)bh * 1024 + s0 + row) * 64 + c];
            Vt[c + 0][row] = bf16_rne(vv.x); Vt[c + 1][row] = bf16_rne(vv.y);
            Vt[c + 2][row] = bf16_rne(vv.z); Vt[c + 3][row] = bf16_rne(vv.w);
            *(float4*)&BiasT[row][c] =
                *(const float4*)&biasbuf[((size_t)bh * 1024 + mt * 64 + row) * 1024 + s0 + c];
        }
        __syncthreads();   // staging visible

        // --- S = Q K^T + bias (bias preloaded into accumulator) ---
        f32x4 s_acc[4];
        #pragma unroll
        for (int nj = 0; nj < 4; ++nj) {
            #pragma unroll
            for (int r = 0; r < 4; ++r)
                s_acc[nj][r] = BiasT[trow + lg * 4 + r][nj * 16 + lr];
            #pragma unroll
            for (int kst = 0; kst < 2; ++kst) {
                const bf16x8 kh = *(const bf16x8*)&Kh[nj * 16 + lr][kst * 32 + lg * 8];
                const bf16x8 kl = *(const bf16x8*)&Kl[nj * 16 + lr][kst * 32 + lg * 8];
                s_acc[nj] = __builtin_amdgcn_mfma_f32_16x16x32_bf16(qh[kst], kl, s_acc[nj], 0, 0, 0);
                s_acc[nj] = __builtin_amdgcn_mfma_f32_16x16x32_bf16(ql[kst], kh, s_acc[nj], 0, 0, 0);
                s_acc[nj] = __builtin_amdgcn_mfma_f32_16x16x32_bf16(qh[kst], kh, s_acc[nj], 0, 0, 0);
            }
        }

        // --- online softmax (rows = trow + lg*4 + r; 16 lanes per row) ---
        float pv[4][4];
        #pragma unroll
        for (int r = 0; r < 4; ++r) {
            float tmax = fmaxf(fmaxf(s_acc[0][r], s_acc[1][r]),
                               fmaxf(s_acc[2][r], s_acc[3][r]));
            #pragma unroll
            for (int off = 8; off > 0; off >>= 1)
                tmax = fmaxf(tmax, __shfl_xor(tmax, off, 16));
            const float newm = fmaxf(mrow[r], tmax);
            const float rescale = __expf(mrow[r] - newm);
            float psum = 0.f;
            #pragma unroll
            for (int nj = 0; nj < 4; ++nj) {
                pv[nj][r] = __expf(s_acc[nj][r] - newm);
                psum += pv[nj][r];
            }
            #pragma unroll
            for (int off = 8; off > 0; off >>= 1)
                psum += __shfl_xor(psum, off, 16);
            lrow[r] = lrow[r] * rescale + psum;
            mrow[r] = newm;
            #pragma unroll
            for (int nj = 0; nj < 4; ++nj) o[nj][r] *= rescale;
        }

        // --- P -> LDS (bf16), wave-private rows; in-wave wait only ---
        #pragma unroll
        for (int nj = 0; nj < 4; ++nj)
            #pragma unroll
            for (int r = 0; r < 4; ++r)
                Pm[trow + lg * 4 + r][nj * 16 + lr] = bf16_rne(pv[nj][r]);
        asm volatile("s_waitcnt lgkmcnt(0)" ::: "memory");
        __builtin_amdgcn_sched_barrier(0);

        // --- O += P V ---
        bf16x8 pa[2];
        pa[0] = *(const bf16x8*)&Pm[trow + lr][lg * 8];
        pa[1] = *(const bf16x8*)&Pm[trow + lr][32 + lg * 8];
        #pragma unroll
        for (int nj = 0; nj < 4; ++nj) {
            #pragma unroll
            for (int kst = 0; kst < 2; ++kst) {
                const bf16x8 vb = *(const bf16x8*)&Vt[nj * 16 + lr][kst * 32 + lg * 8];
                o[nj] = __builtin_amdgcn_mfma_f32_16x16x32_bf16(pa[kst], vb, o[nj], 0, 0, 0);
            }
        }
    }

    // --- epilogue: normalize, write [B,T,E] ---
    #pragma unroll
    for (int r = 0; r < 4; ++r) {
        const int t = mt * 64 + trow + lg * 4 + r;
        const float inv = 1.0f / lrow[r];
        #pragma unroll
        for (int nj = 0; nj < 4; ++nj) {
            const int d = nj * 16 + lr;
            attn[((size_t)b * 1024 + t) * 768 + h * 64 + d] = o[nj][r] * inv;
        }
    }
}

// ---------------------------------------------------------------------------
extern "C" void kernel_launch(void* const* d_in, const int* in_sizes, int n_in,
                              void* d_out, int out_size, void* d_ws, size_t ws_size,
                              hipStream_t stream)
{
    const float* hidden = (const float*)d_in[0];
    const float* kv     = (const float*)d_in[1];
    const float* pos    = (const float*)d_in[2];
    const float* Wq = (const float*)d_in[3];  const float* bq = (const float*)d_in[4];
    const float* Wk = (const float*)d_in[5];  const float* bk = (const float*)d_in[6];
    const float* Wv = (const float*)d_in[7];  const float* bv = (const float*)d_in[8];
    const float* Wo = (const float*)d_in[9];  const float* bo = (const float*)d_in[10];
    float* out = (float*)d_out;

    float* q       = (float*)d_ws;
    float* kbuf    = q     + (size_t)BH * 1024 * 64;
    float* vbuf    = kbuf  + (size_t)BH * 1024 * 64;
    float* attn    = vbuf  + (size_t)BH * 1024 * 64;
    float* biasbuf = attn  + (size_t)BB * 1024 * EE;   // total ~252 MB

    const dim3 gproj(32, 12), blk(256);
    gemm_xwt_mfma<1><<<gproj, blk, 0, stream>>>(hidden, Wq, bq, q,    QSCALE);
    gemm_xwt_mfma<1><<<gproj, blk, 0, stream>>>(kv,     Wk, bk, kbuf, 1.0f);
    gemm_xwt_mfma<1><<<gproj, blk, 0, stream>>>(kv,     Wv, bv, vbuf, 1.0f);

    bias_fill      <<<dim3(1024, 8), 192, 0, stream>>>(q, pos, biasbuf);
    flash_attn_mfma<<<768,           256, 0, stream>>>(q, kbuf, vbuf, biasbuf, attn);

    gemm_xwt_mfma<0><<<gproj, blk, 0, stream>>>(attn, Wo, bo, out, 1.0f);
}